// Round 3
// baseline (625.283 us; speedup 1.0000x reference)
//
#include <hip/hip_runtime.h>
#include <math.h>

#define S 2048
#define DD 2048
#define NH 16
#define DH 128
#define DHID 128
#define DKER 64
#define EPSF 1e-6f

typedef __attribute__((ext_vector_type(8))) short bf16x8;
typedef __attribute__((ext_vector_type(4))) float f32x4;

__device__ __forceinline__ float gelu_f(float x) {
    return 0.5f * x * (1.0f + erff(x * 0.7071067811865475f));
}

__device__ __forceinline__ ushort f2b(float x) {
    uint32_t u = __float_as_uint(x);
    uint32_t r = (u + 0x7FFFu + ((u >> 16) & 1u)) >> 16;
    return (ushort)r;
}

// Y[h,s,e] = gelu( sum_d X[s, h*128+d] * W[h,d,e] ),  e in [0,128)  (fp32 out)
__global__ __launch_bounds__(256) void k_mlp1(const float* __restrict__ X,
                                              const float* __restrict__ Wall,
                                              float* __restrict__ Y) {
    const int h = blockIdx.y;
    const int s0 = blockIdx.x * 64;
    const int tid = threadIdx.x;
    const int ty = tid >> 4, tx = tid & 15;
    __shared__ float Xs[64][20];
    __shared__ float Ws[16][128];
    const float* Wh = Wall + h * DH * DHID;
    float acc[4][8] = {};

    const int lr = tid >> 2, lc = tid & 3;
    const int wr = tid >> 5, wc = tid & 31;
    for (int kc = 0; kc < 8; ++kc) {
        *(float4*)(&Xs[lr][lc * 4]) =
            *(const float4*)(X + (size_t)(s0 + lr) * DD + h * DH + kc * 16 + lc * 4);
        *(float4*)(&Ws[wr][wc * 4]) =
            *(const float4*)(Wh + (kc * 16 + wr) * DHID + wc * 4);
        *(float4*)(&Ws[wr + 8][wc * 4]) =
            *(const float4*)(Wh + (kc * 16 + wr + 8) * DHID + wc * 4);
        __syncthreads();
        #pragma unroll
        for (int kk = 0; kk < 16; ++kk) {
            float a[4];
            #pragma unroll
            for (int i = 0; i < 4; ++i) a[i] = Xs[ty * 4 + i][kk];
            float4 b0 = *(const float4*)(&Ws[kk][tx * 8]);
            float4 b1 = *(const float4*)(&Ws[kk][tx * 8 + 4]);
            #pragma unroll
            for (int i = 0; i < 4; ++i) {
                acc[i][0] += a[i] * b0.x; acc[i][1] += a[i] * b0.y;
                acc[i][2] += a[i] * b0.z; acc[i][3] += a[i] * b0.w;
                acc[i][4] += a[i] * b1.x; acc[i][5] += a[i] * b1.y;
                acc[i][6] += a[i] * b1.z; acc[i][7] += a[i] * b1.w;
            }
        }
        __syncthreads();
    }
    float* Yp = Y + ((size_t)h * S + s0) * DHID;
    #pragma unroll
    for (int i = 0; i < 4; ++i) {
        float4 o0, o1;
        o0.x = gelu_f(acc[i][0]); o0.y = gelu_f(acc[i][1]);
        o0.z = gelu_f(acc[i][2]); o0.w = gelu_f(acc[i][3]);
        o1.x = gelu_f(acc[i][4]); o1.y = gelu_f(acc[i][5]);
        o1.z = gelu_f(acc[i][6]); o1.w = gelu_f(acc[i][7]);
        *(float4*)(Yp + (ty * 4 + i) * DHID + tx * 8) = o0;
        *(float4*)(Yp + (ty * 4 + i) * DHID + tx * 8 + 4) = o1;
    }
}

// Q2abs[h,s,e] = | gelu( Y1[h,s,:] @ W2[h] ) |  -> bf16
__global__ __launch_bounds__(256) void k_mlp2_q(const float* __restrict__ Y1,
                                                const float* __restrict__ Wall,
                                                ushort* __restrict__ Q2) {
    const int h = blockIdx.y;
    const int s0 = blockIdx.x * 64;
    const int tid = threadIdx.x;
    const int ty = tid >> 4, tx = tid & 15;
    __shared__ float Ys[64][20];
    __shared__ float Ws[16][64];
    const float* Wh = Wall + h * DHID * DKER;
    float acc[4][4] = {};
    const int lr = tid >> 2, lc = tid & 3;
    const int wr = tid >> 4, wc = tid & 15;
    for (int kc = 0; kc < 8; ++kc) {
        *(float4*)(&Ys[lr][lc * 4]) =
            *(const float4*)(Y1 + ((size_t)h * S + s0 + lr) * DHID + kc * 16 + lc * 4);
        *(float4*)(&Ws[wr][wc * 4]) =
            *(const float4*)(Wh + (kc * 16 + wr) * DKER + wc * 4);
        __syncthreads();
        #pragma unroll
        for (int kk = 0; kk < 16; ++kk) {
            float4 b = *(const float4*)(&Ws[kk][tx * 4]);
            #pragma unroll
            for (int i = 0; i < 4; ++i) {
                float a = Ys[ty * 4 + i][kk];
                acc[i][0] += a * b.x; acc[i][1] += a * b.y;
                acc[i][2] += a * b.z; acc[i][3] += a * b.w;
            }
        }
        __syncthreads();
    }
    ushort* Qp = Q2 + ((size_t)h * S + s0) * DKER;
    #pragma unroll
    for (int i = 0; i < 4; ++i) {
        ushort4 o;
        o.x = f2b(fabsf(gelu_f(acc[i][0]))); o.y = f2b(fabsf(gelu_f(acc[i][1])));
        o.z = f2b(fabsf(gelu_f(acc[i][2]))); o.w = f2b(fabsf(gelu_f(acc[i][3])));
        *(ushort4*)(Qp + (ty * 4 + i) * DKER + tx * 4) = o;
    }
}

// k2 = |sD| * gelu(Y1k @ Wk2); K3abs = | k2 + (k2 @ Ik) * sD2 |  -> bf16
__global__ __launch_bounds__(256) void k_mlp2_k(const float* __restrict__ Y1,
                                                const float* __restrict__ Wall,
                                                const float* __restrict__ Ikall,
                                                const float* __restrict__ sD,
                                                const float* __restrict__ sD2,
                                                ushort* __restrict__ K3) {
    const int h = blockIdx.y;
    const int s0 = blockIdx.x * 64;
    const int tid = threadIdx.x;
    const int ty = tid >> 4, tx = tid & 15;
    __shared__ float Ys[64][20];
    __shared__ float Ws[16][64];
    __shared__ float K2s[64][68];
    __shared__ float Iks[64][64];
    const float* Wh = Wall + h * DHID * DKER;
    const float* Ikh = Ikall + h * DKER * DKER;
    #pragma unroll
    for (int it = 0; it < 4; ++it) {
        int idx = it * 256 + tid;
        int r = idx >> 4, c = idx & 15;
        *(float4*)(&Iks[r][c * 4]) = *(const float4*)(Ikh + r * DKER + c * 4);
    }
    float acc[4][4] = {};
    const int lr = tid >> 2, lc = tid & 3;
    const int wr = tid >> 4, wc = tid & 15;
    for (int kc = 0; kc < 8; ++kc) {
        *(float4*)(&Ys[lr][lc * 4]) =
            *(const float4*)(Y1 + ((size_t)h * S + s0 + lr) * DHID + kc * 16 + lc * 4);
        *(float4*)(&Ws[wr][wc * 4]) =
            *(const float4*)(Wh + (kc * 16 + wr) * DKER + wc * 4);
        __syncthreads();
        #pragma unroll
        for (int kk = 0; kk < 16; ++kk) {
            float4 b = *(const float4*)(&Ws[kk][tx * 4]);
            #pragma unroll
            for (int i = 0; i < 4; ++i) {
                float a = Ys[ty * 4 + i][kk];
                acc[i][0] += a * b.x; acc[i][1] += a * b.y;
                acc[i][2] += a * b.z; acc[i][3] += a * b.w;
            }
        }
        __syncthreads();
    }
    float sdv[4], sd2v[4];
    #pragma unroll
    for (int j = 0; j < 4; ++j) {
        sdv[j] = fabsf(sD[h * DKER + tx * 4 + j]);
        sd2v[j] = sD2[h * DKER + tx * 4 + j];
    }
    float k2r[4][4];
    #pragma unroll
    for (int i = 0; i < 4; ++i) {
        #pragma unroll
        for (int j = 0; j < 4; ++j) k2r[i][j] = sdv[j] * gelu_f(acc[i][j]);
        float4 o; o.x = k2r[i][0]; o.y = k2r[i][1]; o.z = k2r[i][2]; o.w = k2r[i][3];
        *(float4*)(&K2s[ty * 4 + i][tx * 4]) = o;
    }
    __syncthreads();
    float acc2[4][4] = {};
    #pragma unroll 16
    for (int f = 0; f < 64; ++f) {
        float4 b = *(const float4*)(&Iks[f][tx * 4]);
        #pragma unroll
        for (int i = 0; i < 4; ++i) {
            float a = K2s[ty * 4 + i][f];
            acc2[i][0] += a * b.x; acc2[i][1] += a * b.y;
            acc2[i][2] += a * b.z; acc2[i][3] += a * b.w;
        }
    }
    ushort* Kp = K3 + ((size_t)h * S + s0) * DKER;
    #pragma unroll
    for (int i = 0; i < 4; ++i) {
        ushort4 o;
        o.x = f2b(fabsf(k2r[i][0] + acc2[i][0] * sd2v[0]));
        o.y = f2b(fabsf(k2r[i][1] + acc2[i][1] * sd2v[1]));
        o.z = f2b(fabsf(k2r[i][2] + acc2[i][2] * sd2v[2]));
        o.w = f2b(fabsf(k2r[i][3] + acc2[i][3] * sd2v[3]));
        *(ushort4*)(Kp + (ty * 4 + i) * DKER + tx * 4) = o;
    }
}

// Vt[h][c][t] = bf16( V[t][h*128+c] )
__global__ __launch_bounds__(256) void k_vt(const float* __restrict__ V,
                                            ushort* __restrict__ Vt) {
    const int h = blockIdx.y;
    const int t0 = blockIdx.x * 64;
    const int tid = threadIdx.x;
    __shared__ ushort Ls[128][72];
    #pragma unroll
    for (int it = 0; it < 8; ++it) {
        int idx = it * 256 + tid;
        int r = idx >> 5, c4 = idx & 31;
        float4 v = *(const float4*)(V + (size_t)(t0 + r) * DD + h * DH + c4 * 4);
        Ls[c4 * 4 + 0][r] = f2b(v.x);
        Ls[c4 * 4 + 1][r] = f2b(v.y);
        Ls[c4 * 4 + 2][r] = f2b(v.z);
        Ls[c4 * 4 + 3][r] = f2b(v.w);
    }
    __syncthreads();
    #pragma unroll
    for (int it = 0; it < 4; ++it) {
        int idx = it * 256 + tid;
        int row = idx >> 3, cc = idx & 7;
        *(bf16x8*)(Vt + ((size_t)h * DH + row) * S + t0 + cc * 8) =
            *(const bf16x8*)(&Ls[row][cc * 8]);
    }
}

// pack mask bits: pm[row][w] = bits for cols w*32..w*32+31
__global__ __launch_bounds__(256) void k_mpack(const int* __restrict__ mask,
                                               uint* __restrict__ pm) {
    const int gw = blockIdx.x * 4 + (threadIdx.x >> 6);
    const int lane = threadIdx.x & 63;
    const int row = gw >> 5;       // 32 waves of 64 cols per row
    const int w64 = gw & 31;
    int mv = mask[(size_t)row * S + w64 * 64 + lane];
    unsigned long long b = __ballot(mv != 0);
    if (lane == 0)  pm[row * 64 + w64 * 2]     = (uint)b;
    if (lane == 32) pm[row * 64 + w64 * 2 + 1] = (uint)(b >> 32);
}

// Barrier-free fused attention: all MFMA fragments loaded directly from global
// (A/B frag = contiguous 16B/lane), only the P C->A transpose uses (wave-private)
// LDS. Two-deep register prefetch pipeline for K3/mask/Wsp.
__global__ __launch_bounds__(256, 2) void k_attn(const ushort* __restrict__ Q2,
                                                 const ushort* __restrict__ K3,
                                                 const ushort* __restrict__ Vt,
                                                 const uint* __restrict__ pm,
                                                 const float* __restrict__ Wsp,
                                                 const float* __restrict__ lse,
                                                 float* __restrict__ out) {
    const int h = blockIdx.y;
    const int s0 = blockIdx.x * 64;
    const int tid = threadIdx.x;
    const int wv = tid >> 6;
    const int lane = tid & 63;
    const int ln = lane & 15;
    const int quad = lane >> 4;
    __shared__ ushort Ps[4][16][72];

    const ushort* K3h = K3 + (size_t)h * S * DKER;
    const ushort* Vth = Vt + (size_t)h * DH * S;
    const float*  Wh  = Wsp + (size_t)h * S * S;
    const int srow_q = s0 + wv * 16 + quad * 4;

    // loop-invariant A fragments (Q2 rows s0+wv*16+ln)
    bf16x8 aq[2];
    #pragma unroll
    for (int ks = 0; ks < 2; ++ks)
        aq[ks] = *(const bf16x8*)(Q2 + ((size_t)h * S + s0 + wv * 16 + ln) * DKER +
                                  ks * 32 + quad * 8);

    f32x4 O[8];
    #pragma unroll
    for (int v = 0; v < 8; ++v) O[v] = (f32x4){0.f, 0.f, 0.f, 0.f};
    float rs[4] = {0.f, 0.f, 0.f, 0.f};

    bf16x8 bk[2][2][4];   // [parity][ks][n]
    float  ww[2][4][4];   // [parity][n][r]
    uint2  mw[2][4];      // [parity][r]

#define ISSUE(TILE, P) do {                                                        \
    const int t0_ = (TILE) * 64;                                                   \
    _Pragma("unroll") for (int ks_ = 0; ks_ < 2; ++ks_)                            \
    _Pragma("unroll") for (int n_ = 0; n_ < 4; ++n_)                               \
        bk[P][ks_][n_] = *(const bf16x8*)(K3h +                                    \
            (size_t)(t0_ + n_ * 16 + ln) * DKER + ks_ * 32 + quad * 8);            \
    _Pragma("unroll") for (int r_ = 0; r_ < 4; ++r_)                               \
        mw[P][r_] = *(const uint2*)(pm + (size_t)(srow_q + r_) * 64 + (t0_ >> 5)); \
    _Pragma("unroll") for (int n_ = 0; n_ < 4; ++n_)                               \
    _Pragma("unroll") for (int r_ = 0; r_ < 4; ++r_)                               \
        ww[P][n_][r_] = Wh[(size_t)(srow_q + r_) * S + t0_ + n_ * 16 + ln];        \
} while (0)

#define COMPUTE(TILE, P) do {                                                      \
    const int t0_ = (TILE) * 64;                                                   \
    f32x4 sc[4];                                                                   \
    _Pragma("unroll") for (int n_ = 0; n_ < 4; ++n_)                               \
        sc[n_] = (f32x4){0.f, 0.f, 0.f, 0.f};                                      \
    _Pragma("unroll") for (int ks_ = 0; ks_ < 2; ++ks_)                            \
    _Pragma("unroll") for (int n_ = 0; n_ < 4; ++n_)                               \
        sc[n_] = __builtin_amdgcn_mfma_f32_16x16x32_bf16(aq[ks_], bk[P][ks_][n_],  \
                                                         sc[n_], 0, 0, 0);         \
    _Pragma("unroll") for (int n_ = 0; n_ < 4; ++n_)                               \
    _Pragma("unroll") for (int r_ = 0; r_ < 4; ++r_) {                             \
        uint word = (n_ >= 2) ? mw[P][r_].y : mw[P][r_].x;                         \
        int m_ = (word >> (((n_ & 1) << 4) + ln)) & 1;                             \
        float s_ = sc[n_][r_];                                                     \
        float p_;                                                                  \
        if (m_) { rs[r_] += s_; p_ = s_ + EPSF; }                                  \
        else    { p_ = __expf(ww[P][n_][r_]); }                                    \
        Ps[wv][quad * 4 + r_][n_ * 16 + ln] = f2b(p_);                             \
    }                                                                              \
    _Pragma("unroll") for (int ks_ = 0; ks_ < 2; ++ks_) {                          \
        bf16x8 pf = *(const bf16x8*)&Ps[wv][ln][ks_ * 32 + quad * 8];              \
        _Pragma("unroll") for (int v_ = 0; v_ < 8; ++v_) {                         \
            bf16x8 vf = *(const bf16x8*)(Vth + (size_t)(v_ * 16 + ln) * S + t0_ +  \
                                         ks_ * 32 + quad * 8);                     \
            O[v_] = __builtin_amdgcn_mfma_f32_16x16x32_bf16(pf, vf, O[v_], 0, 0, 0); \
        }                                                                          \
    }                                                                              \
} while (0)

    ISSUE(0, 0);
    for (int it = 0; it < 32; it += 2) {
        ISSUE(it + 1, 1);
        COMPUTE(it, 0);
        if (it + 2 < 32) ISSUE(it + 2, 0);
        COMPUTE(it + 1, 1);
    }
#undef ISSUE
#undef COMPUTE

    // reduce rowsum across the 16 lanes sharing each C/D row
    #pragma unroll
    for (int r = 0; r < 4; ++r) {
        float v = rs[r];
        v += __shfl_xor(v, 1); v += __shfl_xor(v, 2);
        v += __shfl_xor(v, 4); v += __shfl_xor(v, 8);
        rs[r] = v;
    }
    float idv[4];
    #pragma unroll
    for (int r = 0; r < 4; ++r)
        idv[r] = 1.f / (rs[r] + EPSF + expf(lse[(size_t)h * S + srow_q + r]));
    #pragma unroll
    for (int v = 0; v < 8; ++v)
        #pragma unroll
        for (int r = 0; r < 4; ++r)
            out[(size_t)(srow_q + r) * DD + h * DH + v * 16 + ln] = O[v][r] * idv[r];
}

extern "C" void kernel_launch(void* const* d_in, const int* in_sizes, int n_in,
                              void* d_out, int out_size, void* d_ws, size_t ws_size,
                              hipStream_t stream) {
    const float* q   = (const float*)d_in[0];
    const float* k   = (const float*)d_in[1];
    const float* v   = (const float*)d_in[2];
    const int*   msk = (const int*)d_in[3];
    const float* lse = (const float*)d_in[4];
    const float* spw = (const float*)d_in[5];
    const float* wq1 = (const float*)d_in[6];
    const float* wk1 = (const float*)d_in[7];
    const float* wq2 = (const float*)d_in[8];
    const float* wk2 = (const float*)d_in[9];
    const float* ik  = (const float*)d_in[10];
    const float* sD  = (const float*)d_in[11];
    const float* sD2 = (const float*)d_in[12];
    float* out = (float*)d_out;

    float* ws = (float*)d_ws;
    float*  q1  = ws;                                      // 16*2048*128 f32
    float*  k1  = q1 + (size_t)NH * S * DHID;              // 16*2048*128 f32
    ushort* q2b = (ushort*)(k1 + (size_t)NH * S * DHID);   // 16*2048*64 bf16
    ushort* k3b = q2b + (size_t)NH * S * DKER;             // 16*2048*64 bf16
    ushort* vt  = k3b + (size_t)NH * S * DKER;             // 16*128*2048 bf16
    uint*   pm  = (uint*)(vt + (size_t)NH * DH * S);       // 2048*64 u32

    dim3 g(S / 64, NH), b(256);
    k_mpack<<<dim3(S * 32 / 4), b, 0, stream>>>(msk, pm);
    k_mlp1<<<g, b, 0, stream>>>(q, wq1, q1);
    k_mlp1<<<g, b, 0, stream>>>(k, wk1, k1);
    k_mlp2_q<<<g, b, 0, stream>>>(q1, wq2, q2b);
    k_mlp2_k<<<g, b, 0, stream>>>(k1, wk2, ik, sD, sD2, k3b);
    k_vt<<<g, b, 0, stream>>>(v, vt);
    k_attn<<<g, b, 0, stream>>>(q2b, k3b, vt, pm, spw, lse, out);
}

// Round 4
// 515.828 us; speedup vs baseline: 1.2122x; 1.2122x over previous
//
#include <hip/hip_runtime.h>
#include <math.h>

#define S 2048
#define DD 2048
#define NH 16
#define DH 128
#define DHID 128
#define DKER 64
#define EPSF 1e-6f

typedef __attribute__((ext_vector_type(8))) short bf16x8;
typedef __attribute__((ext_vector_type(4))) float f32x4;

__device__ __forceinline__ float gelu_f(float x) {
    return 0.5f * x * (1.0f + erff(x * 0.7071067811865475f));
}

__device__ __forceinline__ ushort f2b(float x) {
    uint32_t u = __float_as_uint(x);
    uint32_t r = (u + 0x7FFFu + ((u >> 16) & 1u)) >> 16;
    return (ushort)r;
}

__device__ __forceinline__ bf16x8 pack8(float4 a, float4 b) {
    bf16x8 r;
    r[0] = (short)f2b(a.x); r[1] = (short)f2b(a.y);
    r[2] = (short)f2b(a.z); r[3] = (short)f2b(a.w);
    r[4] = (short)f2b(b.x); r[5] = (short)f2b(b.y);
    r[6] = (short)f2b(b.z); r[7] = (short)f2b(b.w);
    return r;
}

// ---- weight prep: transpose+convert to bf16 [out_dim][in_dim] ----
__global__ __launch_bounds__(256) void k_wprep(const float* __restrict__ wq1,
                                               const float* __restrict__ wk1,
                                               const float* __restrict__ wq2,
                                               const float* __restrict__ wk2,
                                               const float* __restrict__ ik,
                                               ushort* __restrict__ w1qt,
                                               ushort* __restrict__ w1kt,
                                               ushort* __restrict__ w2qt,
                                               ushort* __restrict__ w2kt,
                                               ushort* __restrict__ ikt) {
    const int h = blockIdx.x, m = blockIdx.y, tid = threadIdx.x;
    const float* src; ushort* dst; int E, D;  // in [D][E] -> out [E][D]
    if (m == 0)      { src = wq1 + h * 16384; dst = w1qt + h * 16384; E = 128; D = 128; }
    else if (m == 1) { src = wk1 + h * 16384; dst = w1kt + h * 16384; E = 128; D = 128; }
    else if (m == 2) { src = wq2 + h * 8192;  dst = w2qt + h * 8192;  E = 64;  D = 128; }
    else if (m == 3) { src = wk2 + h * 8192;  dst = w2kt + h * 8192;  E = 64;  D = 128; }
    else             { src = ik  + h * 4096;  dst = ikt  + h * 4096;  E = 64;  D = 64;  }
    const int dsh = (D == 128) ? 7 : 6;
    const int n = E * D;
    for (int idx = tid; idx < n; idx += 256) {
        int e = idx >> dsh, d = idx & (D - 1);
        dst[idx] = f2b(src[d * E + e]);
    }
}

// ---- fused q path: q2abs = |gelu( gelu(X@W1) @ W2 )| -> bf16 ----
__global__ __launch_bounds__(256) void k_fq(const float* __restrict__ X,
                                            const ushort* __restrict__ w1t,
                                            const ushort* __restrict__ w2t,
                                            ushort* __restrict__ Q2) {
    const int h = blockIdx.y;
    const int s0 = blockIdx.x * 64;
    const int tid = threadIdx.x;
    const int wv = tid >> 6, lane = tid & 63;
    const int ln = lane & 15, quad = lane >> 4;
    __shared__ ushort Y1s[64][136];   // 272B row ≡ 4 dw mod 32 banks

    // A1: X rows (fp32 -> bf16)
    const float* Xr = X + (size_t)(s0 + wv * 16 + ln) * DD + h * DH;
    bf16x8 a1[4];
    #pragma unroll
    for (int ks = 0; ks < 4; ++ks)
        a1[ks] = pack8(*(const float4*)(Xr + ks * 32 + quad * 8),
                       *(const float4*)(Xr + ks * 32 + quad * 8 + 4));

    // mlp1: 64x128 @ 128x128
    const ushort* W1h = w1t + (size_t)h * DH * DHID;
    f32x4 c1[8];
    #pragma unroll
    for (int n = 0; n < 8; ++n) c1[n] = (f32x4){0.f, 0.f, 0.f, 0.f};
    #pragma unroll
    for (int n = 0; n < 8; ++n)
        #pragma unroll
        for (int ks = 0; ks < 4; ++ks) {
            bf16x8 b = *(const bf16x8*)(W1h + (size_t)(n * 16 + ln) * DHID +
                                        ks * 32 + quad * 8);
            c1[n] = __builtin_amdgcn_mfma_f32_16x16x32_bf16(a1[ks], b, c1[n], 0, 0, 0);
        }
    // gelu -> LDS (C-layout scatter; rows are wave-private, same-wave DS order suffices)
    #pragma unroll
    for (int n = 0; n < 8; ++n)
        #pragma unroll
        for (int r = 0; r < 4; ++r)
            Y1s[wv * 16 + quad * 4 + r][n * 16 + ln] = f2b(gelu_f(c1[n][r]));

    // mlp2: 64x128 @ 128x64
    bf16x8 a2[4];
    #pragma unroll
    for (int ks = 0; ks < 4; ++ks)
        a2[ks] = *(const bf16x8*)&Y1s[wv * 16 + ln][ks * 32 + quad * 8];
    const ushort* W2h = w2t + (size_t)h * DKER * DHID;
    f32x4 c2[4];
    #pragma unroll
    for (int n = 0; n < 4; ++n) c2[n] = (f32x4){0.f, 0.f, 0.f, 0.f};
    #pragma unroll
    for (int n = 0; n < 4; ++n)
        #pragma unroll
        for (int ks = 0; ks < 4; ++ks) {
            bf16x8 b = *(const bf16x8*)(W2h + (size_t)(n * 16 + ln) * DHID +
                                        ks * 32 + quad * 8);
            c2[n] = __builtin_amdgcn_mfma_f32_16x16x32_bf16(a2[ks], b, c2[n], 0, 0, 0);
        }
    #pragma unroll
    for (int n = 0; n < 4; ++n)
        #pragma unroll
        for (int r = 0; r < 4; ++r)
            Q2[((size_t)h * S + s0 + wv * 16 + quad * 4 + r) * DKER + n * 16 + ln] =
                f2b(fabsf(gelu_f(c2[n][r])));
}

// ---- fused k path: k2=|sD|*gelu(gelu(X@W1)@W2); k3=|k2 + (k2@Ik)*sD2| ----
__global__ __launch_bounds__(256) void k_fk(const float* __restrict__ X,
                                            const ushort* __restrict__ w1t,
                                            const ushort* __restrict__ w2t,
                                            const ushort* __restrict__ ikt,
                                            const float* __restrict__ sD,
                                            const float* __restrict__ sD2,
                                            ushort* __restrict__ K3) {
    const int h = blockIdx.y;
    const int s0 = blockIdx.x * 64;
    const int tid = threadIdx.x;
    const int wv = tid >> 6, lane = tid & 63;
    const int ln = lane & 15, quad = lane >> 4;
    __shared__ ushort Y1s[64][136];
    __shared__ ushort K2s[64][72];

    const float* Xr = X + (size_t)(s0 + wv * 16 + ln) * DD + h * DH;
    bf16x8 a1[4];
    #pragma unroll
    for (int ks = 0; ks < 4; ++ks)
        a1[ks] = pack8(*(const float4*)(Xr + ks * 32 + quad * 8),
                       *(const float4*)(Xr + ks * 32 + quad * 8 + 4));

    const ushort* W1h = w1t + (size_t)h * DH * DHID;
    f32x4 c1[8];
    #pragma unroll
    for (int n = 0; n < 8; ++n) c1[n] = (f32x4){0.f, 0.f, 0.f, 0.f};
    #pragma unroll
    for (int n = 0; n < 8; ++n)
        #pragma unroll
        for (int ks = 0; ks < 4; ++ks) {
            bf16x8 b = *(const bf16x8*)(W1h + (size_t)(n * 16 + ln) * DHID +
                                        ks * 32 + quad * 8);
            c1[n] = __builtin_amdgcn_mfma_f32_16x16x32_bf16(a1[ks], b, c1[n], 0, 0, 0);
        }
    #pragma unroll
    for (int n = 0; n < 8; ++n)
        #pragma unroll
        for (int r = 0; r < 4; ++r)
            Y1s[wv * 16 + quad * 4 + r][n * 16 + ln] = f2b(gelu_f(c1[n][r]));

    bf16x8 a2[4];
    #pragma unroll
    for (int ks = 0; ks < 4; ++ks)
        a2[ks] = *(const bf16x8*)&Y1s[wv * 16 + ln][ks * 32 + quad * 8];
    const ushort* W2h = w2t + (size_t)h * DKER * DHID;
    f32x4 c2[4];
    #pragma unroll
    for (int n = 0; n < 4; ++n) c2[n] = (f32x4){0.f, 0.f, 0.f, 0.f};
    #pragma unroll
    for (int n = 0; n < 4; ++n)
        #pragma unroll
        for (int ks = 0; ks < 4; ++ks) {
            bf16x8 b = *(const bf16x8*)(W2h + (size_t)(n * 16 + ln) * DHID +
                                        ks * 32 + quad * 8);
            c2[n] = __builtin_amdgcn_mfma_f32_16x16x32_bf16(a2[ks], b, c2[n], 0, 0, 0);
        }
    // k2 = |sD| * gelu  (per-lane col = n*16+ln)
    float k2v[4][4];
    float sdv[4], sd2v[4];
    #pragma unroll
    for (int n = 0; n < 4; ++n) {
        sdv[n]  = fabsf(sD[h * DKER + n * 16 + ln]);
        sd2v[n] = sD2[h * DKER + n * 16 + ln];
    }
    #pragma unroll
    for (int n = 0; n < 4; ++n)
        #pragma unroll
        for (int r = 0; r < 4; ++r) {
            k2v[n][r] = sdv[n] * gelu_f(c2[n][r]);
            K2s[wv * 16 + quad * 4 + r][n * 16 + ln] = f2b(k2v[n][r]);
        }
    // interaction: (64x64) @ Ik(64x64)
    bf16x8 a3[2];
    #pragma unroll
    for (int ks = 0; ks < 2; ++ks)
        a3[ks] = *(const bf16x8*)&K2s[wv * 16 + ln][ks * 32 + quad * 8];
    const ushort* Ikh = ikt + (size_t)h * DKER * DKER;
    f32x4 c3[4];
    #pragma unroll
    for (int n = 0; n < 4; ++n) c3[n] = (f32x4){0.f, 0.f, 0.f, 0.f};
    #pragma unroll
    for (int n = 0; n < 4; ++n)
        #pragma unroll
        for (int ks = 0; ks < 2; ++ks) {
            bf16x8 b = *(const bf16x8*)(Ikh + (size_t)(n * 16 + ln) * DKER +
                                        ks * 32 + quad * 8);
            c3[n] = __builtin_amdgcn_mfma_f32_16x16x32_bf16(a3[ks], b, c3[n], 0, 0, 0);
        }
    #pragma unroll
    for (int n = 0; n < 4; ++n)
        #pragma unroll
        for (int r = 0; r < 4; ++r)
            K3[((size_t)h * S + s0 + wv * 16 + quad * 4 + r) * DKER + n * 16 + ln] =
                f2b(fabsf(k2v[n][r] + c3[n][r] * sd2v[n]));
}

// ---- Vt[h][c][t] = bf16( V[t][h*128+c] ) ----
__global__ __launch_bounds__(256) void k_vt(const float* __restrict__ V,
                                            ushort* __restrict__ Vt) {
    const int h = blockIdx.y;
    const int t0 = blockIdx.x * 64;
    const int tid = threadIdx.x;
    __shared__ ushort Ls[128][72];
    #pragma unroll
    for (int it = 0; it < 8; ++it) {
        int idx = it * 256 + tid;
        int r = idx >> 5, c4 = idx & 31;
        float4 v = *(const float4*)(V + (size_t)(t0 + r) * DD + h * DH + c4 * 4);
        Ls[c4 * 4 + 0][r] = f2b(v.x);
        Ls[c4 * 4 + 1][r] = f2b(v.y);
        Ls[c4 * 4 + 2][r] = f2b(v.z);
        Ls[c4 * 4 + 3][r] = f2b(v.w);
    }
    __syncthreads();
    #pragma unroll
    for (int it = 0; it < 4; ++it) {
        int idx = it * 256 + tid;
        int row = idx >> 3, cc = idx & 7;
        *(bf16x8*)(Vt + ((size_t)h * DH + row) * S + t0 + cc * 8) =
            *(const bf16x8*)(&Ls[row][cc * 8]);
    }
}

// ---- pack mask bits ----
__global__ __launch_bounds__(256) void k_mpack(const int* __restrict__ mask,
                                               uint* __restrict__ pm) {
    const int gw = blockIdx.x * 4 + (threadIdx.x >> 6);
    const int lane = threadIdx.x & 63;
    const int row = gw >> 5;
    const int w64 = gw & 31;
    int mv = mask[(size_t)row * S + w64 * 64 + lane];
    unsigned long long b = __ballot(mv != 0);
    if (lane == 0)  pm[row * 64 + w64 * 2]     = (uint)b;
    if (lane == 32) pm[row * 64 + w64 * 2 + 1] = (uint)(b >> 32);
}

// ---- fused attention, split-t: each z-half does 16 tiles of 64, writes
//      partial O (no invd) and partial masked rowsum ----
__global__ __launch_bounds__(256, 4) void k_attn(const ushort* __restrict__ Q2,
                                                 const ushort* __restrict__ K3,
                                                 const ushort* __restrict__ Vt,
                                                 const uint* __restrict__ pm,
                                                 const float* __restrict__ Wsp,
                                                 float* __restrict__ Op,
                                                 float* __restrict__ rsp) {
    const int h = blockIdx.y;
    const int s0 = blockIdx.x * 64;
    const int z = blockIdx.z;
    const int tbase = z * (S / 2);
    const int tid = threadIdx.x;
    const int wv = tid >> 6, lane = tid & 63;
    const int ln = lane & 15, quad = lane >> 4;
    __shared__ ushort K3s[64][72];
    __shared__ ushort Vts[128][72];
    __shared__ ushort Ps[4][16][72];

    const ushort* K3h = K3 + (size_t)h * S * DKER;
    const ushort* Vth = Vt + (size_t)h * DH * S;
    const float*  Wh  = Wsp + (size_t)h * S * S;
    const int srow_q = s0 + wv * 16 + quad * 4;

    // loop-invariant A fragments (Q2 rows), direct from global
    bf16x8 aq[2];
    #pragma unroll
    for (int ks = 0; ks < 2; ++ks)
        aq[ks] = *(const bf16x8*)(Q2 + ((size_t)h * S + s0 + wv * 16 + ln) * DKER +
                                  ks * 32 + quad * 8);

    f32x4 O[8];
    #pragma unroll
    for (int v = 0; v < 8; ++v) O[v] = (f32x4){0.f, 0.f, 0.f, 0.f};
    float rs[4] = {0.f, 0.f, 0.f, 0.f};

    for (int it = 0; it < 16; ++it) {
        const int t0 = tbase + it * 64;
        __syncthreads();
        // stage K3 tile 64x64 (2 chunks/thread) and Vt tile 128x64 (4 chunks/thread)
        #pragma unroll
        for (int c = 0; c < 2; ++c) {
            int idx = c * 256 + tid;
            int r = idx >> 3, cc = idx & 7;
            *(bf16x8*)&K3s[r][cc * 8] =
                *(const bf16x8*)(K3h + (size_t)(t0 + r) * DKER + cc * 8);
        }
        #pragma unroll
        for (int c = 0; c < 4; ++c) {
            int idx = c * 256 + tid;
            int r = idx >> 3, cc = idx & 7;
            *(bf16x8*)&Vts[r][cc * 8] =
                *(const bf16x8*)(Vth + (size_t)r * S + t0 + cc * 8);
        }
        __syncthreads();
        // per-lane mask words + sparse weights (global; overlap score MFMAs)
        uint2 mw[4];
        #pragma unroll
        for (int r = 0; r < 4; ++r)
            mw[r] = *(const uint2*)(pm + (size_t)(srow_q + r) * 64 + (t0 >> 5));
        float ww[4][4];
        #pragma unroll
        for (int n = 0; n < 4; ++n)
            #pragma unroll
            for (int r = 0; r < 4; ++r)
                ww[n][r] = Wh[(size_t)(srow_q + r) * S + t0 + n * 16 + ln];

        // scores
        f32x4 sc[4];
        #pragma unroll
        for (int n = 0; n < 4; ++n) sc[n] = (f32x4){0.f, 0.f, 0.f, 0.f};
        #pragma unroll
        for (int ks = 0; ks < 2; ++ks)
            #pragma unroll
            for (int n = 0; n < 4; ++n) {
                bf16x8 bf = *(const bf16x8*)&K3s[n * 16 + ln][ks * 32 + quad * 8];
                sc[n] = __builtin_amdgcn_mfma_f32_16x16x32_bf16(aq[ks], bf, sc[n], 0, 0, 0);
            }
        // P transform + rowsum
        #pragma unroll
        for (int n = 0; n < 4; ++n)
            #pragma unroll
            for (int r = 0; r < 4; ++r) {
                uint word = (n >= 2) ? mw[r].y : mw[r].x;
                int m = (word >> (((n & 1) << 4) + ln)) & 1;
                float s = sc[n][r];
                float p;
                if (m) { rs[r] += s; p = s + EPSF; }
                else   { p = __expf(ww[n][r]); }
                Ps[wv][quad * 4 + r][n * 16 + ln] = f2b(p);
            }
        // PV (same-wave LDS roundtrip; HW per-wave DS ordering)
        #pragma unroll
        for (int ks = 0; ks < 2; ++ks) {
            bf16x8 pf = *(const bf16x8*)&Ps[wv][ln][ks * 32 + quad * 8];
            #pragma unroll
            for (int v = 0; v < 8; ++v) {
                bf16x8 vf = *(const bf16x8*)&Vts[v * 16 + ln][ks * 32 + quad * 8];
                O[v] = __builtin_amdgcn_mfma_f32_16x16x32_bf16(pf, vf, O[v], 0, 0, 0);
            }
        }
    }
    // partial rowsum: reduce across the 16 lanes sharing each C/D row
    #pragma unroll
    for (int r = 0; r < 4; ++r) {
        float v = rs[r];
        v += __shfl_xor(v, 1); v += __shfl_xor(v, 2);
        v += __shfl_xor(v, 4); v += __shfl_xor(v, 8);
        rs[r] = v;
    }
    if (ln == 0) {
        #pragma unroll
        for (int r = 0; r < 4; ++r)
            rsp[((size_t)z * NH + h) * S + srow_q + r] = rs[r];
    }
    #pragma unroll
    for (int v = 0; v < 8; ++v)
        #pragma unroll
        for (int r = 0; r < 4; ++r)
            Op[(((size_t)z * NH + h) * S + srow_q + r) * DH + v * 16 + ln] = O[v][r];
}

// ---- combine halves, apply invd ----
__global__ __launch_bounds__(256) void k_comb(const float* __restrict__ Op,
                                              const float* __restrict__ rsp,
                                              const float* __restrict__ lse,
                                              float* __restrict__ out) {
    const int h = blockIdx.y;
    const int s0 = blockIdx.x * 64;
    const int tid = threadIdx.x;
    const int c = (tid & 31) * 4;
    const int r0 = tid >> 5;
    for (int rr = r0; rr < 64; rr += 8) {
        const int row = s0 + rr;
        float rs = rsp[(size_t)h * S + row] + rsp[((size_t)NH + h) * S + row];
        float idv = 1.f / (rs + EPSF + expf(lse[(size_t)h * S + row]));
        float4 a = *(const float4*)(Op + ((size_t)h * S + row) * DH + c);
        float4 b = *(const float4*)(Op + (((size_t)NH + h) * S + row) * DH + c);
        float4 o;
        o.x = (a.x + b.x) * idv; o.y = (a.y + b.y) * idv;
        o.z = (a.z + b.z) * idv; o.w = (a.w + b.w) * idv;
        *(float4*)(out + (size_t)row * DD + h * DH + c) = o;
    }
}

extern "C" void kernel_launch(void* const* d_in, const int* in_sizes, int n_in,
                              void* d_out, int out_size, void* d_ws, size_t ws_size,
                              hipStream_t stream) {
    const float* q   = (const float*)d_in[0];
    const float* k   = (const float*)d_in[1];
    const float* v   = (const float*)d_in[2];
    const int*   msk = (const int*)d_in[3];
    const float* lse = (const float*)d_in[4];
    const float* spw = (const float*)d_in[5];
    const float* wq1 = (const float*)d_in[6];
    const float* wk1 = (const float*)d_in[7];
    const float* wq2 = (const float*)d_in[8];
    const float* wk2 = (const float*)d_in[9];
    const float* ik  = (const float*)d_in[10];
    const float* sD  = (const float*)d_in[11];
    const float* sD2 = (const float*)d_in[12];
    float* out = (float*)d_out;

    ushort* q2b  = (ushort*)d_ws;                          // 16*2048*64
    ushort* k3b  = q2b + (size_t)NH * S * DKER;            // 16*2048*64
    ushort* vt   = k3b + (size_t)NH * S * DKER;            // 16*128*2048
    uint*   pm   = (uint*)(vt + (size_t)NH * DH * S);      // 2048*64
    ushort* w1qt = (ushort*)(pm + (size_t)S * 64);         // 16*128*128
    ushort* w1kt = w1qt + (size_t)NH * DH * DHID;
    ushort* w2qt = w1kt + (size_t)NH * DH * DHID;          // 16*64*128
    ushort* w2kt = w2qt + (size_t)NH * DKER * DHID;
    ushort* ikt  = w2kt + (size_t)NH * DKER * DHID;        // 16*64*64
    float*  Op   = (float*)(ikt + (size_t)NH * DKER * DKER);  // 2*16*2048*128
    float*  rsp  = Op + (size_t)2 * NH * S * DH;           // 2*16*2048

    dim3 g(S / 64, NH), b(256);
    k_wprep<<<dim3(NH, 5), b, 0, stream>>>(wq1, wk1, wq2, wk2, ik,
                                           w1qt, w1kt, w2qt, w2kt, ikt);
    k_mpack<<<dim3(S * 32 / 4), b, 0, stream>>>(msk, pm);
    k_vt<<<g, b, 0, stream>>>(v, vt);
    k_fq<<<g, b, 0, stream>>>(q, w1qt, w2qt, q2b);
    k_fk<<<g, b, 0, stream>>>(k, w1kt, w2kt, ikt, sD, sD2, k3b);
    k_attn<<<dim3(S / 64, NH, 2), b, 0, stream>>>(q2b, k3b, vt, pm, spw, Op, rsp);
    k_comb<<<g, b, 0, stream>>>(Op, rsp, lse, out);
}

// Round 5
// 494.148 us; speedup vs baseline: 1.2654x; 1.0439x over previous
//
#include <hip/hip_runtime.h>
#include <math.h>

#define S 2048
#define DD 2048
#define NH 16
#define DH 128
#define DHID 128
#define DKER 64
#define EPSF 1e-6f

typedef __attribute__((ext_vector_type(8))) short bf16x8;
typedef __attribute__((ext_vector_type(4))) float f32x4;

__device__ __forceinline__ float gelu_f(float x) {
    return 0.5f * x * (1.0f + erff(x * 0.7071067811865475f));
}

__device__ __forceinline__ ushort f2b(float x) {
    uint32_t u = __float_as_uint(x);
    uint32_t r = (u + 0x7FFFu + ((u >> 16) & 1u)) >> 16;
    return (ushort)r;
}

__device__ __forceinline__ bf16x8 pack8(float4 a, float4 b) {
    bf16x8 r;
    r[0] = (short)f2b(a.x); r[1] = (short)f2b(a.y);
    r[2] = (short)f2b(a.z); r[3] = (short)f2b(a.w);
    r[4] = (short)f2b(b.x); r[5] = (short)f2b(b.y);
    r[6] = (short)f2b(b.z); r[7] = (short)f2b(b.w);
    return r;
}

// ---- weight prep: transpose+convert to bf16 [out_dim][in_dim] ----
__global__ __launch_bounds__(256) void k_wprep(const float* __restrict__ wq1,
                                               const float* __restrict__ wk1,
                                               const float* __restrict__ wq2,
                                               const float* __restrict__ wk2,
                                               const float* __restrict__ ik,
                                               ushort* __restrict__ w1qt,
                                               ushort* __restrict__ w1kt,
                                               ushort* __restrict__ w2qt,
                                               ushort* __restrict__ w2kt,
                                               ushort* __restrict__ ikt) {
    const int h = blockIdx.x, m = blockIdx.y, tid = threadIdx.x;
    const float* src; ushort* dst; int D;
    if (m == 0)      { src = wq1 + h * 16384; dst = w1qt + h * 16384; D = 128; }
    else if (m == 1) { src = wk1 + h * 16384; dst = w1kt + h * 16384; D = 128; }
    else if (m == 2) { src = wq2 + h * 8192;  dst = w2qt + h * 8192;  D = 128; }
    else if (m == 3) { src = wk2 + h * 8192;  dst = w2kt + h * 8192;  D = 128; }
    else             { src = ik  + h * 4096;  dst = ikt  + h * 4096;  D = 64;  }
    const int E = (m == 0 || m == 1) ? 128 : 64;
    const int dsh = (D == 128) ? 7 : 6;
    const int n = E * D;
    for (int idx = tid; idx < n; idx += 256) {
        int e = idx >> dsh, d = idx & (D - 1);
        dst[idx] = f2b(src[d * E + e]);
    }
}

// ---- fused MLP paths: z=0 -> Q2abs, z=1 -> K3abs ----
__global__ __launch_bounds__(256) void k_fused(const float* __restrict__ Xq,
                                               const float* __restrict__ Xk,
                                               const ushort* __restrict__ w1qt,
                                               const ushort* __restrict__ w1kt,
                                               const ushort* __restrict__ w2qt,
                                               const ushort* __restrict__ w2kt,
                                               const ushort* __restrict__ ikt,
                                               const float* __restrict__ sD,
                                               const float* __restrict__ sD2,
                                               ushort* __restrict__ Q2,
                                               ushort* __restrict__ K3) {
    const int h = blockIdx.y;
    const int s0 = blockIdx.x * 64;
    const int z = blockIdx.z;
    const int tid = threadIdx.x;
    const int wv = tid >> 6, lane = tid & 63;
    const int ln = lane & 15, quad = lane >> 4;
    __shared__ ushort Y1s[64][136];   // 272B row ≡ 4 dw mod 32 banks
    __shared__ ushort K2s[64][72];

    const float* X = z ? Xk : Xq;
    const ushort* w1t = z ? w1kt : w1qt;
    const ushort* w2t = z ? w2kt : w2qt;

    // A1: X rows (fp32 -> bf16), direct from global
    const float* Xr = X + (size_t)(s0 + wv * 16 + ln) * DD + h * DH;
    bf16x8 a1[4];
    #pragma unroll
    for (int ks = 0; ks < 4; ++ks)
        a1[ks] = pack8(*(const float4*)(Xr + ks * 32 + quad * 8),
                       *(const float4*)(Xr + ks * 32 + quad * 8 + 4));

    // mlp1: 64x128 @ 128x128
    const ushort* W1h = w1t + (size_t)h * DH * DHID;
    f32x4 c1[8];
    #pragma unroll
    for (int n = 0; n < 8; ++n) c1[n] = (f32x4){0.f, 0.f, 0.f, 0.f};
    #pragma unroll
    for (int n = 0; n < 8; ++n)
        #pragma unroll
        for (int ks = 0; ks < 4; ++ks) {
            bf16x8 b = *(const bf16x8*)(W1h + (size_t)(n * 16 + ln) * DHID +
                                        ks * 32 + quad * 8);
            c1[n] = __builtin_amdgcn_mfma_f32_16x16x32_bf16(a1[ks], b, c1[n], 0, 0, 0);
        }
    #pragma unroll
    for (int n = 0; n < 8; ++n)
        #pragma unroll
        for (int r = 0; r < 4; ++r)
            Y1s[wv * 16 + quad * 4 + r][n * 16 + ln] = f2b(gelu_f(c1[n][r]));

    // mlp2: 64x128 @ 128x64  (rows are wave-private; same-wave DS ordering)
    bf16x8 a2[4];
    #pragma unroll
    for (int ks = 0; ks < 4; ++ks)
        a2[ks] = *(const bf16x8*)&Y1s[wv * 16 + ln][ks * 32 + quad * 8];
    const ushort* W2h = w2t + (size_t)h * DKER * DHID;
    f32x4 c2[4];
    #pragma unroll
    for (int n = 0; n < 4; ++n) c2[n] = (f32x4){0.f, 0.f, 0.f, 0.f};
    #pragma unroll
    for (int n = 0; n < 4; ++n)
        #pragma unroll
        for (int ks = 0; ks < 4; ++ks) {
            bf16x8 b = *(const bf16x8*)(W2h + (size_t)(n * 16 + ln) * DHID +
                                        ks * 32 + quad * 8);
            c2[n] = __builtin_amdgcn_mfma_f32_16x16x32_bf16(a2[ks], b, c2[n], 0, 0, 0);
        }

    if (z == 0) {
        #pragma unroll
        for (int n = 0; n < 4; ++n)
            #pragma unroll
            for (int r = 0; r < 4; ++r)
                Q2[((size_t)h * S + s0 + wv * 16 + quad * 4 + r) * DKER + n * 16 + ln] =
                    f2b(fabsf(gelu_f(c2[n][r])));
        return;
    }

    // k path: k2 = |sD| * gelu; k3 = |k2 + (k2 @ Ik) * sD2|
    float k2v[4][4];
    float sdv[4], sd2v[4];
    #pragma unroll
    for (int n = 0; n < 4; ++n) {
        sdv[n]  = fabsf(sD[h * DKER + n * 16 + ln]);
        sd2v[n] = sD2[h * DKER + n * 16 + ln];
    }
    #pragma unroll
    for (int n = 0; n < 4; ++n)
        #pragma unroll
        for (int r = 0; r < 4; ++r) {
            k2v[n][r] = sdv[n] * gelu_f(c2[n][r]);
            K2s[wv * 16 + quad * 4 + r][n * 16 + ln] = f2b(k2v[n][r]);
        }
    bf16x8 a3[2];
    #pragma unroll
    for (int ks = 0; ks < 2; ++ks)
        a3[ks] = *(const bf16x8*)&K2s[wv * 16 + ln][ks * 32 + quad * 8];
    const ushort* Ikh = ikt + (size_t)h * DKER * DKER;
    f32x4 c3[4];
    #pragma unroll
    for (int n = 0; n < 4; ++n) c3[n] = (f32x4){0.f, 0.f, 0.f, 0.f};
    #pragma unroll
    for (int n = 0; n < 4; ++n)
        #pragma unroll
        for (int ks = 0; ks < 2; ++ks) {
            bf16x8 b = *(const bf16x8*)(Ikh + (size_t)(n * 16 + ln) * DKER +
                                        ks * 32 + quad * 8);
            c3[n] = __builtin_amdgcn_mfma_f32_16x16x32_bf16(a3[ks], b, c3[n], 0, 0, 0);
        }
    #pragma unroll
    for (int n = 0; n < 4; ++n)
        #pragma unroll
        for (int r = 0; r < 4; ++r)
            K3[((size_t)h * S + s0 + wv * 16 + quad * 4 + r) * DKER + n * 16 + ln] =
                f2b(fabsf(k2v[n][r] + c3[n][r] * sd2v[n]));
}

// ---- Vt[h][c][t] = bf16( V[t][h*128+c] ) ----
__global__ __launch_bounds__(256) void k_vt(const float* __restrict__ V,
                                            ushort* __restrict__ Vt) {
    const int h = blockIdx.y;
    const int t0 = blockIdx.x * 64;
    const int tid = threadIdx.x;
    __shared__ ushort Ls[128][72];
    #pragma unroll
    for (int it = 0; it < 8; ++it) {
        int idx = it * 256 + tid;
        int r = idx >> 5, c4 = idx & 31;
        float4 v = *(const float4*)(V + (size_t)(t0 + r) * DD + h * DH + c4 * 4);
        Ls[c4 * 4 + 0][r] = f2b(v.x);
        Ls[c4 * 4 + 1][r] = f2b(v.y);
        Ls[c4 * 4 + 2][r] = f2b(v.z);
        Ls[c4 * 4 + 3][r] = f2b(v.w);
    }
    __syncthreads();
    #pragma unroll
    for (int it = 0; it < 4; ++it) {
        int idx = it * 256 + tid;
        int row = idx >> 3, cc = idx & 7;
        *(bf16x8*)(Vt + ((size_t)h * DH + row) * S + t0 + cc * 8) =
            *(const bf16x8*)(&Ls[row][cc * 8]);
    }
}

// ---- pack mask bits ----
__global__ __launch_bounds__(256) void k_mpack(const int* __restrict__ mask,
                                               uint* __restrict__ pm) {
    const int gw = blockIdx.x * 4 + (threadIdx.x >> 6);
    const int lane = threadIdx.x & 63;
    const int row = gw >> 5;
    const int w64 = gw & 31;
    int mv = mask[(size_t)row * S + w64 * 64 + lane];
    unsigned long long b = __ballot(mv != 0);
    if (lane == 0)  pm[row * 64 + w64 * 2]     = (uint)b;
    if (lane == 32) pm[row * 64 + w64 * 2 + 1] = (uint)(b >> 32);
}

// ---- fused attention, one-iteration register prefetch pipeline ----
// Staging: global->reg (iter i+1 issued during compute of i) -> LDS (top of i+1).
// Wsp/mask rotate through a double-buffered register set so the cold-HBM
// latency overlaps a full compute phase.
__global__ __launch_bounds__(256, 2) void k_attn(const ushort* __restrict__ Q2,
                                                 const ushort* __restrict__ K3,
                                                 const ushort* __restrict__ Vt,
                                                 const uint* __restrict__ pm,
                                                 const float* __restrict__ Wsp,
                                                 const float* __restrict__ lse,
                                                 float* __restrict__ out) {
    const int h = blockIdx.y;
    const int s0 = blockIdx.x * 64;
    const int tid = threadIdx.x;
    const int wv = tid >> 6, lane = tid & 63;
    const int ln = lane & 15, quad = lane >> 4;
    __shared__ ushort K3s[64][72];
    __shared__ ushort Vts[128][72];
    __shared__ ushort Ps[4][16][72];

    const ushort* K3h = K3 + (size_t)h * S * DKER;
    const ushort* Vth = Vt + (size_t)h * DH * S;
    const float*  Wh  = Wsp + (size_t)h * S * S;
    const int srow_q = s0 + wv * 16 + quad * 4;
    const int rk = tid >> 3, ck = tid & 7;   // staging coords (rows rk, rk+32,...)

    // loop-invariant A fragments (Q2 rows), direct from global (R3/R4-verified)
    bf16x8 aq[2];
    #pragma unroll
    for (int ks = 0; ks < 2; ++ks)
        aq[ks] = *(const bf16x8*)(Q2 + ((size_t)h * S + s0 + wv * 16 + ln) * DKER +
                                  ks * 32 + quad * 8);

    f32x4 O[8];
    #pragma unroll
    for (int v = 0; v < 8; ++v) O[v] = (f32x4){0.f, 0.f, 0.f, 0.f};
    float rs[4] = {0.f, 0.f, 0.f, 0.f};

    bf16x8 sk[2][2], sv[2][4];   // [parity][chunk] staged K3 / Vt tiles
    float  ww[2][4][4];          // [parity][n][r] sparse weights
    uint2  mw[2][4];             // [parity][r] packed mask

#define PREF(T, P) do {                                                            \
    if ((T) < 32) {                                                                \
        const int t0_ = (T) * 64;                                                  \
        _Pragma("unroll") for (int c_ = 0; c_ < 2; ++c_)                           \
            sk[P][c_] = *(const bf16x8*)(K3h +                                     \
                (size_t)(t0_ + rk + c_ * 32) * DKER + ck * 8);                     \
        _Pragma("unroll") for (int c_ = 0; c_ < 4; ++c_)                           \
            sv[P][c_] = *(const bf16x8*)(Vth +                                     \
                (size_t)(rk + c_ * 32) * S + t0_ + ck * 8);                        \
        _Pragma("unroll") for (int r_ = 0; r_ < 4; ++r_)                           \
            mw[P][r_] = *(const uint2*)(pm + (size_t)(srow_q + r_) * 64 +          \
                                        (t0_ >> 5));                               \
        _Pragma("unroll") for (int n_ = 0; n_ < 4; ++n_)                           \
        _Pragma("unroll") for (int r_ = 0; r_ < 4; ++r_)                           \
            ww[P][n_][r_] = Wh[(size_t)(srow_q + r_) * S + t0_ + n_ * 16 + ln];    \
    }                                                                              \
} while (0)

#define STEP(T, P, PN) do {                                                        \
    __syncthreads();  /* prior LDS consumers done */                               \
    _Pragma("unroll") for (int c_ = 0; c_ < 2; ++c_)                               \
        *(bf16x8*)&K3s[rk + c_ * 32][ck * 8] = sk[P][c_];                          \
    _Pragma("unroll") for (int c_ = 0; c_ < 4; ++c_)                               \
        *(bf16x8*)&Vts[rk + c_ * 32][ck * 8] = sv[P][c_];                          \
    __syncthreads();  /* staged tile visible */                                    \
    PREF((T) + 1, PN);  /* next tile's globals: consumed after next barriers */    \
    f32x4 sc[4];                                                                   \
    _Pragma("unroll") for (int n_ = 0; n_ < 4; ++n_)                               \
        sc[n_] = (f32x4){0.f, 0.f, 0.f, 0.f};                                      \
    _Pragma("unroll") for (int ks_ = 0; ks_ < 2; ++ks_)                            \
    _Pragma("unroll") for (int n_ = 0; n_ < 4; ++n_) {                             \
        bf16x8 bf = *(const bf16x8*)&K3s[n_ * 16 + ln][ks_ * 32 + quad * 8];       \
        sc[n_] = __builtin_amdgcn_mfma_f32_16x16x32_bf16(aq[ks_], bf, sc[n_],      \
                                                         0, 0, 0);                  \
    }                                                                              \
    _Pragma("unroll") for (int n_ = 0; n_ < 4; ++n_)                               \
    _Pragma("unroll") for (int r_ = 0; r_ < 4; ++r_) {                             \
        uint word = (n_ >= 2) ? mw[P][r_].y : mw[P][r_].x;                         \
        int m_ = (word >> (((n_ & 1) << 4) + ln)) & 1;                             \
        float s_ = sc[n_][r_];                                                     \
        float p_;                                                                  \
        if (m_) { rs[r_] += s_; p_ = s_ + EPSF; }                                  \
        else    { p_ = __expf(ww[P][n_][r_]); }                                    \
        Ps[wv][quad * 4 + r_][n_ * 16 + ln] = f2b(p_);                             \
    }                                                                              \
    _Pragma("unroll") for (int ks_ = 0; ks_ < 2; ++ks_) {                          \
        bf16x8 pf = *(const bf16x8*)&Ps[wv][ln][ks_ * 32 + quad * 8];              \
        _Pragma("unroll") for (int v_ = 0; v_ < 8; ++v_) {                         \
            bf16x8 vf = *(const bf16x8*)&Vts[v_ * 16 + ln][ks_ * 32 + quad * 8];   \
            O[v_] = __builtin_amdgcn_mfma_f32_16x16x32_bf16(pf, vf, O[v_],         \
                                                            0, 0, 0);               \
        }                                                                          \
    }                                                                              \
} while (0)

    PREF(0, 0);
    for (int it = 0; it < 32; it += 2) {
        STEP(it, 0, 1);
        STEP(it + 1, 1, 0);
    }
#undef PREF
#undef STEP

    // rowsum across the 16 lanes sharing each C/D row
    #pragma unroll
    for (int r = 0; r < 4; ++r) {
        float v = rs[r];
        v += __shfl_xor(v, 1); v += __shfl_xor(v, 2);
        v += __shfl_xor(v, 4); v += __shfl_xor(v, 8);
        rs[r] = v;
    }
    float idv[4];
    #pragma unroll
    for (int r = 0; r < 4; ++r)
        idv[r] = 1.f / (rs[r] + EPSF + expf(lse[(size_t)h * S + srow_q + r]));
    #pragma unroll
    for (int v = 0; v < 8; ++v)
        #pragma unroll
        for (int r = 0; r < 4; ++r)
            out[(size_t)(srow_q + r) * DD + h * DH + v * 16 + ln] = O[v][r] * idv[r];
}

extern "C" void kernel_launch(void* const* d_in, const int* in_sizes, int n_in,
                              void* d_out, int out_size, void* d_ws, size_t ws_size,
                              hipStream_t stream) {
    const float* q   = (const float*)d_in[0];
    const float* k   = (const float*)d_in[1];
    const float* v   = (const float*)d_in[2];
    const int*   msk = (const int*)d_in[3];
    const float* lse = (const float*)d_in[4];
    const float* spw = (const float*)d_in[5];
    const float* wq1 = (const float*)d_in[6];
    const float* wk1 = (const float*)d_in[7];
    const float* wq2 = (const float*)d_in[8];
    const float* wk2 = (const float*)d_in[9];
    const float* ik  = (const float*)d_in[10];
    const float* sD  = (const float*)d_in[11];
    const float* sD2 = (const float*)d_in[12];
    float* out = (float*)d_out;

    ushort* q2b  = (ushort*)d_ws;                          // 16*2048*64
    ushort* k3b  = q2b + (size_t)NH * S * DKER;            // 16*2048*64
    ushort* vt   = k3b + (size_t)NH * S * DKER;            // 16*128*2048
    uint*   pm   = (uint*)(vt + (size_t)NH * DH * S);      // 2048*64
    ushort* w1qt = (ushort*)(pm + (size_t)S * 64);         // 16*128*128
    ushort* w1kt = w1qt + (size_t)NH * DH * DHID;
    ushort* w2qt = w1kt + (size_t)NH * DH * DHID;          // 16*64*128
    ushort* w2kt = w2qt + (size_t)NH * DKER * DHID;
    ushort* ikt  = w2kt + (size_t)NH * DKER * DHID;        // 16*64*64

    dim3 g(S / 64, NH), b(256);
    k_wprep<<<dim3(NH, 5), b, 0, stream>>>(wq1, wk1, wq2, wk2, ik,
                                           w1qt, w1kt, w2qt, w2kt, ikt);
    k_mpack<<<dim3(S * 32 / 4), b, 0, stream>>>(msk, pm);
    k_vt<<<g, b, 0, stream>>>(v, vt);
    k_fused<<<dim3(S / 64, NH, 2), b, 0, stream>>>(q, k, w1qt, w1kt, w2qt, w2kt,
                                                   ikt, sD, sD2, q2b, k3b);
    k_attn<<<g, b, 0, stream>>>(q2b, k3b, vt, pm, spw, lse, out);
}